// Round 11
// baseline (442.733 us; speedup 1.0000x reference)
//
#include <hip/hip_runtime.h>
#include <math.h>

#define DD 128
#define HH 16
#define EPSV 1e-5f

static __device__ __forceinline__ ushort f2bf(float f) {
  uint u = __float_as_uint(f);
  u += 0x7FFFu + ((u >> 16) & 1u);
  return (ushort)(u >> 16);
}
static __device__ __forceinline__ float bflo(uint u) { return __uint_as_float(u << 16); }
static __device__ __forceinline__ float bfhi(uint u) { return __uint_as_float(u & 0xFFFF0000u); }

// ---------------- degree histogram ----------------

__global__ void k_hist(const int* __restrict__ dst, int* __restrict__ deg, int ecnt) {
  int stride = gridDim.x * blockDim.x;
  for (int e = blockIdx.x * blockDim.x + threadIdx.x; e < ecnt; e += stride)
    atomicAdd(&deg[dst[e]], 1);
}

// ---------------- scans (padded-to-8 degrees) ----------------

#define SCAN_T 1024
#define SCAN_I 4

__global__ void k_scan1(const int* __restrict__ deg, int* __restrict__ bsum, int n) {
  __shared__ int sh[SCAN_T];
  int tid = threadIdx.x;
  int base = blockIdx.x * SCAN_T * SCAN_I + tid * SCAN_I;
  int s = 0;
#pragma unroll
  for (int j = 0; j < SCAN_I; ++j) {
    int i = base + j;
    if (i < n) s += (deg[i] + 7) & ~7;
  }
  sh[tid] = s;
  __syncthreads();
  for (int off = SCAN_T / 2; off > 0; off >>= 1) {
    if (tid < off) sh[tid] += sh[tid + off];
    __syncthreads();
  }
  if (tid == 0) bsum[blockIdx.x] = sh[0];
}

// scan2: padded exclusive prefix -> rowoff & cursor; dinv; writes pad CSR entries (=n)
__global__ void k_scan2(const int* __restrict__ deg, const int* __restrict__ bsum,
                        int* __restrict__ rowoff, int* __restrict__ cursor,
                        float* __restrict__ dinv, ushort* __restrict__ csr, int n) {
  __shared__ int sh[SCAN_T];
  __shared__ int sbase;
  int tid = threadIdx.x;
  int b = blockIdx.x;
  if (tid == 0) { int s = 0; for (int j = 0; j < b; ++j) s += bsum[j]; sbase = s; }
  int base = b * SCAN_T * SCAN_I + tid * SCAN_I;
  int d[SCAN_I], dp[SCAN_I]; int ts = 0;
#pragma unroll
  for (int j = 0; j < SCAN_I; ++j) {
    int i = base + j;
    d[j] = (i < n) ? deg[i] : 0;
    dp[j] = (d[j] + 7) & ~7;
    ts += dp[j];
  }
  sh[tid] = ts;
  __syncthreads();
  for (int off = 1; off < SCAN_T; off <<= 1) {
    int v = (tid >= off) ? sh[tid - off] : 0;
    __syncthreads();
    sh[tid] += v;
    __syncthreads();
  }
  int ex = sbase + sh[tid] - ts;
#pragma unroll
  for (int j = 0; j < SCAN_I; ++j) {
    int i = base + j;
    if (i < n) {
      rowoff[i] = ex;
      cursor[i] = ex;
      dinv[i] = rsqrtf((float)d[j] + 2.0f);
      for (int k = d[j]; k < dp[j]; ++k) csr[ex + k] = (ushort)n;  // pad -> zero row
    }
    ex += dp[j];
    if (i == n - 1) rowoff[n] = ex;
  }
}

// ---------------- GEMM1 (fp32 A, xdinv epilogue) fused with CSR fill ----------------

static __device__ __forceinline__ void gemm_f32_body(
    const float* __restrict__ A, const float* __restrict__ B,
    const float* __restrict__ dinv, ushort* __restrict__ C, int nrows, int bx,
    float* Bs) {
  int tid = threadIdx.x;
  int tx = tid & 15, ty = tid >> 4;
  int rowbase = (bx >> 1) * 128;
  int c0 = (bx & 1) * 64;
  {
    int kk = tid >> 4;
    int cc = (tid & 15) * 4;
#pragma unroll
    for (int p = 0; p < 8; ++p) {
      int k = p * 16 + kk;
      float4 bv = *reinterpret_cast<const float4*>(&B[k * DD + c0 + cc]);
      *reinterpret_cast<float4*>(&Bs[k * 64 + cc]) = bv;
    }
  }
  __syncthreads();
  float acc[8][4];
#pragma unroll
  for (int i = 0; i < 8; ++i)
#pragma unroll
    for (int j = 0; j < 4; ++j) acc[i][j] = 0.f;
  int rl[8];
#pragma unroll
  for (int i = 0; i < 8; ++i) {
    int r = rowbase + ty * 8 + i;
    rl[i] = (r < nrows) ? r : (nrows - 1);
  }
  const float4* A4 = reinterpret_cast<const float4*>(A);
  for (int kq = 0; kq < 32; ++kq) {
    float4 av[8];
#pragma unroll
    for (int i = 0; i < 8; ++i) av[i] = A4[(size_t)rl[i] * 32 + kq];
#pragma unroll
    for (int j = 0; j < 4; ++j) {
      float4 bv = *reinterpret_cast<const float4*>(&Bs[(kq * 4 + j) * 64 + tx * 4]);
#pragma unroll
      for (int i = 0; i < 8; ++i) {
        float a = (j == 0) ? av[i].x : (j == 1) ? av[i].y : (j == 2) ? av[i].z : av[i].w;
        acc[i][0] = fmaf(a, bv.x, acc[i][0]);
        acc[i][1] = fmaf(a, bv.y, acc[i][1]);
        acc[i][2] = fmaf(a, bv.z, acc[i][2]);
        acc[i][3] = fmaf(a, bv.w, acc[i][3]);
      }
    }
  }
  int cbase = c0 + tx * 4;
#pragma unroll
  for (int i = 0; i < 8; ++i) {
    int r = rowbase + ty * 8 + i;
    if (r < nrows) {
      float dv = dinv[r];
      ushort4 o;
      o.x = f2bf(acc[i][0] * dv); o.y = f2bf(acc[i][1] * dv);
      o.z = f2bf(acc[i][2] * dv); o.w = f2bf(acc[i][3] * dv);
      *reinterpret_cast<ushort4*>(&C[(size_t)r * DD + cbase]) = o;
    }
  }
}

__global__ __launch_bounds__(256) void k_gemm1_fill(
    const float* __restrict__ A, const float* __restrict__ B,
    const float* __restrict__ dinv, ushort* __restrict__ C, int nrows,
    const int* __restrict__ src, const int* __restrict__ dst,
    int* __restrict__ cursor, ushort* __restrict__ csr, int ecnt,
    int gblocks, int fblocks) {
  __shared__ float Bs[DD * 64];
  int bx = blockIdx.x;
  if (bx < gblocks) {
    gemm_f32_body(A, B, dinv, C, nrows, bx, Bs);
  } else {
    int stride = fblocks * 256;
    for (int e = (bx - gblocks) * 256 + threadIdx.x; e < ecnt; e += stride) {
      int s = src[e], d = dst[e];
      int idx = atomicAdd(&cursor[d], 1);
      __builtin_nontemporal_store((ushort)s, &csr[idx]);
    }
  }
}

// ---------------- GEMM2: bf16 A @ f32 B, xdinv epilogue -> bf16 ----------------

__global__ __launch_bounds__(256) void k_gemmb(const ushort* __restrict__ A,
                                               const float* __restrict__ B,
                                               const float* __restrict__ dinv,
                                               ushort* __restrict__ C, int nrows) {
  __shared__ float Bs[DD * 64];
  int tid = threadIdx.x;
  int tx = tid & 15, ty = tid >> 4;
  int rowbase = (blockIdx.x >> 1) * 128;
  int c0 = (blockIdx.x & 1) * 64;
  {
    int kk = tid >> 4;
    int cc = (tid & 15) * 4;
#pragma unroll
    for (int p = 0; p < 8; ++p) {
      int k = p * 16 + kk;
      float4 bv = *reinterpret_cast<const float4*>(&B[k * DD + c0 + cc]);
      *reinterpret_cast<float4*>(&Bs[k * 64 + cc]) = bv;
    }
  }
  __syncthreads();
  float acc[8][4];
#pragma unroll
  for (int i = 0; i < 8; ++i)
#pragma unroll
    for (int j = 0; j < 4; ++j) acc[i][j] = 0.f;
  int rl[8];
#pragma unroll
  for (int i = 0; i < 8; ++i) {
    int r = rowbase + ty * 8 + i;
    rl[i] = (r < nrows) ? r : (nrows - 1);
  }
  const uint4* A16 = reinterpret_cast<const uint4*>(A);  // 16B = 8 bf16
  for (int kq = 0; kq < 16; ++kq) {
    uint4 av[8];
#pragma unroll
    for (int i = 0; i < 8; ++i) av[i] = A16[(size_t)rl[i] * 16 + kq];
#pragma unroll
    for (int kk = 0; kk < 8; ++kk) {
      float4 bv = *reinterpret_cast<const float4*>(&Bs[(kq * 8 + kk) * 64 + tx * 4]);
#pragma unroll
      for (int i = 0; i < 8; ++i) {
        uint w = (kk < 2) ? av[i].x : (kk < 4) ? av[i].y : (kk < 6) ? av[i].z : av[i].w;
        float a = (kk & 1) ? bfhi(w) : bflo(w);
        acc[i][0] = fmaf(a, bv.x, acc[i][0]);
        acc[i][1] = fmaf(a, bv.y, acc[i][1]);
        acc[i][2] = fmaf(a, bv.z, acc[i][2]);
        acc[i][3] = fmaf(a, bv.w, acc[i][3]);
      }
    }
  }
  int cbase = c0 + tx * 4;
#pragma unroll
  for (int i = 0; i < 8; ++i) {
    int r = rowbase + ty * 8 + i;
    if (r < nrows) {
      float dv = dinv[r];
      ushort4 o;
      o.x = f2bf(acc[i][0] * dv); o.y = f2bf(acc[i][1] * dv);
      o.z = f2bf(acc[i][2] * dv); o.w = f2bf(acc[i][3] * dv);
      *reinterpret_cast<ushort4*>(&C[(size_t)r * DD + cbase]) = o;
    }
  }
}

// ---------------- edge accumulate: unweighted gather-sum, u16 CSR ----------------
// Wave = node i; lane owns dims {2*lane, 2*lane+1}. Lists are 8-entry aligned and
// padded with src=n (zero row), so the loop is pure full batches: one scalar uint4
// load = 8 srcs, 8 gathers, 16 adds. Prefetch next batch under the gathers.

static __device__ __forceinline__ void edge_accum(
    const uint* __restrict__ xw32, const ushort* __restrict__ csr,
    int start, int cnt, uint lane, float& acc0, float& acc1) {
  const uint4* cs = (const uint4*)(csr + __builtin_amdgcn_readfirstlane(start));
  int rem = __builtin_amdgcn_readfirstlane(cnt);
  uint4 c;
  if (rem >= 8) c = *cs++;
  while (rem >= 16) {
    uint v[8];
    v[0] = xw32[((c.x & 0xFFFFu) << 6) + lane];
    v[1] = xw32[((c.x >> 16) << 6) + lane];
    v[2] = xw32[((c.y & 0xFFFFu) << 6) + lane];
    v[3] = xw32[((c.y >> 16) << 6) + lane];
    v[4] = xw32[((c.z & 0xFFFFu) << 6) + lane];
    v[5] = xw32[((c.z >> 16) << 6) + lane];
    v[6] = xw32[((c.w & 0xFFFFu) << 6) + lane];
    v[7] = xw32[((c.w >> 16) << 6) + lane];
    uint4 cn = *cs++;
#pragma unroll
    for (int j = 0; j < 8; ++j) {
      acc0 += bflo(v[j]);
      acc1 += bfhi(v[j]);
    }
    c = cn; rem -= 8;
  }
  if (rem >= 8) {
    uint v[8];
    v[0] = xw32[((c.x & 0xFFFFu) << 6) + lane];
    v[1] = xw32[((c.x >> 16) << 6) + lane];
    v[2] = xw32[((c.y & 0xFFFFu) << 6) + lane];
    v[3] = xw32[((c.y >> 16) << 6) + lane];
    v[4] = xw32[((c.z & 0xFFFFu) << 6) + lane];
    v[5] = xw32[((c.z >> 16) << 6) + lane];
    v[6] = xw32[((c.w & 0xFFFFu) << 6) + lane];
    v[7] = xw32[((c.w >> 16) << 6) + lane];
#pragma unroll
    for (int j = 0; j < 8; ++j) {
      acc0 += bflo(v[j]);
      acc1 += bfhi(v[j]);
    }
  }
}

// ---------------- agg1: gather-sum + di scale + bias + LN + ReLU -> bf16 h1 ------------

__global__ __launch_bounds__(256) void k_agg1(
    const ushort* __restrict__ xwd, const ushort* __restrict__ csr,
    const int* __restrict__ rowoff, const float* __restrict__ dinv,
    const float* __restrict__ bias, const float* __restrict__ gam,
    const float* __restrict__ bet, uint* __restrict__ outp, int n) {
  int wv = threadIdx.x >> 6, lane = threadIdx.x & 63;
  int i = blockIdx.x * 4 + wv;
  if (i >= n) return;
  int start = rowoff[i], cnt = rowoff[i + 1] - start;
  float di = dinv[i];
  const uint* xw32 = (const uint*)xwd;
  float acc0 = 0.f, acc1 = 0.f;
  edge_accum(xw32, csr, start, cnt, (uint)lane, acc0, acc1);
  // conv = di*(sum + 2*xwd[i]) + b   (xwd already has dinv folded in)
  uint su = xw32[((uint)i << 6) + lane];
  float2 bv = ((const float2*)bias)[lane];
  float c0v = fmaf(di, acc0 + 2.f * bflo(su), bv.x);
  float c1v = fmaf(di, acc1 + 2.f * bfhi(su), bv.y);
  // LayerNorm over 128 dims (wave-local)
  float s = c0v + c1v;
#pragma unroll
  for (int off = 32; off > 0; off >>= 1) s += __shfl_xor(s, off);
  float mu = s * (1.f / DD);
  float c0 = c0v - mu, c1 = c1v - mu;
  float q = c0 * c0 + c1 * c1;
#pragma unroll
  for (int off = 32; off > 0; off >>= 1) q += __shfl_xor(q, off);
  float rstd = rsqrtf(q * (1.f / DD) + EPSV);
  float2 gv = ((const float2*)gam)[lane];
  float2 tv = ((const float2*)bet)[lane];
  float h0 = fmaxf(fmaf(c0 * rstd, gv.x, tv.x), 0.f);
  float h1 = fmaxf(fmaf(c1 * rstd, gv.y, tv.y), 0.f);
  uint packed = (uint)f2bf(h0) | ((uint)f2bf(h1) << 16);
  __builtin_nontemporal_store(packed, &outp[((uint)i << 6) + lane]);
}

// ---------------- agg2: gather-sum + LN + SE + residual + ReLU -> fp32 out -------------

__global__ __launch_bounds__(256) void k_agg2(
    const ushort* __restrict__ xwd, const ushort* __restrict__ csr,
    const int* __restrict__ rowoff, const float* __restrict__ dinv,
    const float* __restrict__ bias, const float* __restrict__ gam,
    const float* __restrict__ bet, const float* __restrict__ Ws,
    const float* __restrict__ bs, const float* __restrict__ We,
    const float* __restrict__ be, const float* __restrict__ xin,
    float* __restrict__ outp, int n) {
  int wv = threadIdx.x >> 6, lane = threadIdx.x & 63;
  int i = blockIdx.x * 4 + wv;
  if (i >= n) return;
  int start = rowoff[i], cnt = rowoff[i + 1] - start;
  float di = dinv[i];
  const uint* xw32 = (const uint*)xwd;
  float acc0 = 0.f, acc1 = 0.f;
  edge_accum(xw32, csr, start, cnt, (uint)lane, acc0, acc1);
  uint su = xw32[((uint)i << 6) + lane];
  float2 bv = ((const float2*)bias)[lane];
  float c0v = fmaf(di, acc0 + 2.f * bflo(su), bv.x);
  float c1v = fmaf(di, acc1 + 2.f * bfhi(su), bv.y);
  // LayerNorm
  float s = c0v + c1v;
#pragma unroll
  for (int off = 32; off > 0; off >>= 1) s += __shfl_xor(s, off);
  float mu = s * (1.f / DD);
  float c0 = c0v - mu, c1 = c1v - mu;
  float q = c0 * c0 + c1 * c1;
#pragma unroll
  for (int off = 32; off > 0; off >>= 1) q += __shfl_xor(q, off);
  float rstd = rsqrtf(q * (1.f / DD) + EPSV);
  float2 gv = ((const float2*)gam)[lane];
  float2 tv = ((const float2*)bet)[lane];
  float h0 = fmaf(c0 * rstd, gv.x, tv.x);
  float h1 = fmaf(c1 * rstd, gv.y, tv.y);
  // SE: s16 = relu(h @ Ws + bs); w = sigmoid(s16 @ We + be)
  float pj[HH];
  const float* wr0 = &Ws[(2 * lane) * HH];
  const float* wr1 = &Ws[(2 * lane + 1) * HH];
#pragma unroll
  for (int j = 0; j < HH; ++j) pj[j] = h0 * wr0[j] + h1 * wr1[j];
#pragma unroll
  for (int off = 32; off > 0; off >>= 1) {
#pragma unroll
    for (int j = 0; j < HH; ++j) pj[j] += __shfl_xor(pj[j], off);
  }
  float2 bev = ((const float2*)be)[lane];
  float wacc0 = bev.x, wacc1 = bev.y;
#pragma unroll
  for (int j = 0; j < HH; ++j) {
    float sj = fmaxf(pj[j] + bs[j], 0.f);
    float2 wev = ((const float2*)(We + j * DD))[lane];
    wacc0 = fmaf(sj, wev.x, wacc0);
    wacc1 = fmaf(sj, wev.y, wacc1);
  }
  float w0 = 1.f / (1.f + __expf(-wacc0));
  float w1 = 1.f / (1.f + __expf(-wacc1));
  float2 xr = ((const float2*)(xin + (size_t)i * DD))[lane];
  float2 o;
  o.x = fmaxf(fmaf(h0, w0, xr.x), 0.f);
  o.y = fmaxf(fmaf(h1, w1, xr.y), 0.f);
  ((float2*)(outp + (size_t)i * DD))[lane] = o;
}

// ---------------- launcher ----------------

extern "C" void kernel_launch(void* const* d_in, const int* in_sizes, int n_in,
                              void* d_out, int out_size, void* d_ws, size_t ws_size,
                              hipStream_t stream) {
  const float* x   = (const float*)d_in[0];
  const int*   ei  = (const int*)d_in[1];
  const float* W1  = (const float*)d_in[2];
  const float* b1  = (const float*)d_in[3];
  const float* g1  = (const float*)d_in[4];
  const float* be1 = (const float*)d_in[5];
  const float* W2  = (const float*)d_in[6];
  const float* b2  = (const float*)d_in[7];
  const float* g2  = (const float*)d_in[8];
  const float* be2 = (const float*)d_in[9];
  const float* Ws  = (const float*)d_in[10];
  const float* bs  = (const float*)d_in[11];
  const float* We  = (const float*)d_in[12];
  const float* bee = (const float*)d_in[13];
  float* outp = (float*)d_out;

  int n    = in_sizes[0] / DD;
  int ecnt = in_sizes[1] / 2;
  const int* src = ei;
  const int* dst = ei + ecnt;

  char* w = (char*)d_ws;
  ushort* xwd   = (ushort*)w; w += (size_t)(n + 1) * DD * 2;  // row n = zero row
  uint*   h1    = (uint*)w;   w += (size_t)n * DD * 2;        // bf16 packed
  int*    deg   = (int*)w;    w += (size_t)n * 4;
  int*    cursor= (int*)w;    w += (size_t)n * 4;
  int*    rowoff= (int*)w;    w += (size_t)(n + 1) * 4;
  float*  dinv  = (float*)w;  w += (size_t)n * 4;
  int*    bsum  = (int*)w;    w += 64 * 4;
  w = (char*)(((size_t)w + 15) & ~(size_t)15);
  ushort* csr   = (ushort*)w; w += ((size_t)ecnt + 8 * (size_t)n + 16) * 2;

  hipMemsetAsync(deg, 0, (size_t)n * 4, stream);
  hipMemsetAsync(xwd + (size_t)n * DD, 0, DD * 2, stream);  // zero row

  const int TB = 256;
  k_hist<<<2048, TB, 0, stream>>>(dst, deg, ecnt);
  int nb = (n + SCAN_T * SCAN_I - 1) / (SCAN_T * SCAN_I);
  k_scan1<<<nb, SCAN_T, 0, stream>>>(deg, bsum, n);
  k_scan2<<<nb, SCAN_T, 0, stream>>>(deg, bsum, rowoff, cursor, dinv, csr, n);

  int gblocks = ((n + 127) / 128) * 2;
  int fblocks = 2048;
  k_gemm1_fill<<<gblocks + fblocks, TB, 0, stream>>>(x, W1, dinv, xwd, n,
                                                     src, dst, cursor, csr, ecnt,
                                                     gblocks, fblocks);
  int nb4 = (n + 3) / 4;
  k_agg1<<<nb4, TB, 0, stream>>>(xwd, csr, rowoff, dinv, b1, g1, be1, h1, n);
  k_gemmb<<<gblocks, TB, 0, stream>>>((const ushort*)h1, W2, dinv, xwd, n);
  k_agg2<<<nb4, TB, 0, stream>>>(xwd, csr, rowoff, dinv, b2, g2, be2,
                                 Ws, bs, We, bee, x, outp, n);
}